// Round 6
// baseline (227.901 us; speedup 1.0000x reference)
//
#include <hip/hip_runtime.h>

#define NCH   256
#define NPROT 320
#define HW    16384      // 128*128
#define TAU   20.0f
#define EPSN  1e-4f

// ---------------------------------------------------------------------------
// Kernel 1a: avg-pool sup_x (5,256,128,128) over 16x16 cells -> praw[p][c]
// One block per (s,c) plane. Fully coalesced float4 reads; no atomics.
// ---------------------------------------------------------------------------
__global__ __launch_bounds__(256) void k_pool(const float* __restrict__ sup_x,
                                              float* __restrict__ praw) {
    int b = blockIdx.x;            // s*256 + c
    int t = threadIdx.x;
    const float4* plane = (const float4*)(sup_x + (size_t)b * HW);
    float rsum[8];
    #pragma unroll
    for (int r = 0; r < 8; ++r) rsum[r] = 0.f;
    #pragma unroll
    for (int i = 0; i < 16; ++i) {
        float4 v = plane[i * 256 + t];          // h = i*8 + (t>>5), w4 = t&31
        rsum[i >> 1] += v.x + v.y + v.z + v.w;  // cell row R = h>>4 = i>>1
    }
    __shared__ float part[8][256];
    #pragma unroll
    for (int r = 0; r < 8; ++r) part[r][t] = rsum[r];
    __syncthreads();
    int R  = t >> 5;
    int cw = t & 31;               // = C*4 + bsub
    float s = 0.f;
    #pragma unroll
    for (int a = 0; a < 8; ++a) s += part[R][a * 32 + cw];
    s += __shfl_xor(s, 1);
    s += __shfl_xor(s, 2);
    if ((t & 3) == 0) {
        int shot = b >> 8, c = b & 255;
        int p = shot * 64 + R * 8 + (cw >> 2);
        praw[(size_t)p * NCH + c] = s * (1.0f / 256.0f);
    }
}

// ---------------------------------------------------------------------------
// Kernel 1b: per-proto center + safe-normalize; PT transposed (float4 per
// 4-channel block, proto-major within block); sp[p] = sum_c pro_n[p][c].
// ---------------------------------------------------------------------------
__device__ __forceinline__ float block_sum256(float x, float* ws4, int t) {
    #pragma unroll
    for (int o = 1; o < 64; o <<= 1) x += __shfl_xor(x, o);
    if ((t & 63) == 0) ws4[t >> 6] = x;
    __syncthreads();
    float r = ws4[0] + ws4[1] + ws4[2] + ws4[3];
    __syncthreads();
    return r;
}

__global__ __launch_bounds__(256) void k_norm(const float* __restrict__ praw,
                                              float* __restrict__ PT,
                                              float* __restrict__ sp) {
    int p = blockIdx.x;
    int c = threadIdx.x;
    __shared__ float ws4[4];
    float v = praw[p * NCH + c];
    float mean = block_sum256(v, ws4, c) * (1.0f / 256.0f);
    float cen = v - mean;
    float n2 = block_sum256(cen * cen, ws4, c);
    float inv = 1.0f / fmaxf(sqrtf(n2), EPSN);
    float pn = cen * inv;
    PT[(size_t)(c >> 2) * NPROT * 4 + p * 4 + (c & 3)] = pn;
    float ssum = block_sum256(pn, ws4, c);
    if (c == 0) sp[p] = ssum;
}

// ---------------------------------------------------------------------------
// Kernel 2: fused normalize(qry) -> 320 dots -> softmax-weighted mean + argmax
// 8 pixels/block, 256 threads = 4 waves; grid 2048 = 8 blocks/CU
// -> 8 waves/SIMD (VGPR ~45 <= 64 cap from __launch_bounds__(256,8)).
// Wave w owns pixels {2w, 2w+1}; lane l owns protos {l + 64j, j=0..4}.
// TLP (8 waves/SIMD) hides the ~300-cyc L1/L2 PT load latency; per cb each
// wave does 5 coalesced float4 PT loads + 2 broadcast LDS q-reads + 40 FMAs.
// ---------------------------------------------------------------------------
__global__ __launch_bounds__(256, 8) void k_main(const float* __restrict__ qry,
                                                 const float* __restrict__ PT,
                                                 const float* __restrict__ sp,
                                                 float* __restrict__ out) {
    // smem layout (floats):
    //  [0, 2080)      qlds 8 x 260   (after FMA aliased: M/Sa/Ta/Ia 4 x (8 x 65))
    //  [2080, 2336)   stats s1 [32][8]  (after stage1 aliased: P2m/s/t/i 4 x 72)
    //  [2336, 2592)   stats s2 [32][8]
    //  [2592, 2600)   meanv ; [2600, 2608) invnv
    __shared__ __align__(16) float smem[2608];
    int t = threadIdx.x;
    int pixbase = blockIdx.x * 8;

    // ---- stage 8 pixels x 256 channels (coalesced float4 over pixel dim) ----
    {
        int f4 = t & 1;            // float4-of-pixels (0..1)
        int c0 = t >> 1;           // 0..127
        #pragma unroll
        for (int i = 0; i < 2; ++i) {
            int c = c0 + 128 * i;
            float4 v = *(const float4*)(qry + (size_t)c * HW + pixbase + f4 * 4);
            int px = f4 * 4;
            smem[(px + 0) * 260 + c] = v.x;
            smem[(px + 1) * 260 + c] = v.y;
            smem[(px + 2) * 260 + c] = v.z;
            smem[(px + 3) * 260 + c] = v.w;
        }
    }
    __syncthreads();

    // ---- per-pixel mean and inverse safe-norm ----
    {
        int pix = t & 7, sub = t >> 3;      // 32 subs x 8 channels
        float s1 = 0.f, s2 = 0.f;
        #pragma unroll
        for (int j = 0; j < 8; ++j) {
            float q = smem[pix * 260 + sub * 8 + j];
            s1 += q; s2 += q * q;
        }
        smem[2080 + sub * 8 + pix] = s1;
        smem[2336 + sub * 8 + pix] = s2;
    }
    __syncthreads();
    if (t < 8) {
        float s1 = 0.f, s2 = 0.f;
        #pragma unroll
        for (int j = 0; j < 32; ++j) { s1 += smem[2080 + j * 8 + t]; s2 += smem[2336 + j * 8 + t]; }
        float mean = s1 * (1.0f / 256.0f);
        float n2 = fmaxf(s2 - s1 * mean, 0.f);
        smem[2592 + t] = mean;
        smem[2600 + t] = 1.0f / fmaxf(sqrtf(n2), EPSN);
    }
    __syncthreads();

    // ---- dot products: 2 pixels x 5 protos per thread ----
    int lane = t & 63;
    int w = t >> 6;
    float acc[2][5];
    #pragma unroll
    for (int i = 0; i < 2; ++i)
        #pragma unroll
        for (int j = 0; j < 5; ++j) acc[i][j] = 0.f;

    const float4* P4 = (const float4*)PT + lane;
    const float* qrow = smem + (w * 2) * 260;

    #pragma unroll 2
    for (int cb = 0; cb < 64; ++cb) {
        const float4* Pn = P4 + (size_t)cb * NPROT;
        float4 pv[5];
        #pragma unroll
        for (int j = 0; j < 5; ++j) pv[j] = Pn[j * 64];
        #pragma unroll
        for (int i = 0; i < 2; ++i) {
            float4 qv = *(const float4*)(qrow + i * 260 + cb * 4);
            #pragma unroll
            for (int j = 0; j < 5; ++j) {
                acc[i][j] = fmaf(qv.x, pv[j].x, acc[i][j]);
                acc[i][j] = fmaf(qv.y, pv[j].y, acc[i][j]);
                acc[i][j] = fmaf(qv.z, pv[j].z, acc[i][j]);
                acc[i][j] = fmaf(qv.w, pv[j].w, acc[i][j]);
            }
        }
    }

    // ---- per-thread softmax partials over 5 protos, per pixel ----
    float spv[5];
    #pragma unroll
    for (int j = 0; j < 5; ++j) spv[j] = sp[lane + 64 * j];

    float m2[2], S2[2], T2[2], I2[2];
    #pragma unroll
    for (int i = 0; i < 2; ++i) {
        int pix = w * 2 + i;
        float mean = smem[2592 + pix], invn = smem[2600 + pix];
        float d[5];
        float m = -1e30f; int bj = 0;
        #pragma unroll
        for (int j = 0; j < 5; ++j) {
            d[j] = TAU * invn * (acc[i][j] - mean * spv[j]);
            if (d[j] > m) { m = d[j]; bj = j; }
        }
        float S = 0.f, T = 0.f;
        #pragma unroll
        for (int j = 0; j < 5; ++j) {
            float e = __expf(d[j] - m);
            S += e; T += e * d[j];
        }
        m2[i] = m; S2[i] = S; T2[i] = T; I2[i] = (float)(lane + 64 * bj);
    }
    __syncthreads();   // all waves done reading qlds; safe to alias

    float* M  = smem;            // 8 x 65
    float* Sa = smem + 520;
    float* Ta = smem + 1040;
    float* Ia = smem + 1560;
    #pragma unroll
    for (int i = 0; i < 2; ++i) {
        int pix = w * 2 + i;
        M [pix * 65 + lane] = m2[i];
        Sa[pix * 65 + lane] = S2[i];
        Ta[pix * 65 + lane] = T2[i];
        Ia[pix * 65 + lane] = I2[i];
    }
    __syncthreads();

    // ---- stage 2: merge 8 lanes per (pixel, octant) ----
    float* P2m = smem + 2080;    // 8 x 9
    float* P2s = smem + 2152;
    float* P2t = smem + 2224;
    float* P2i = smem + 2296;
    if (t < 64) {
        int pix = t >> 3, oct = t & 7;
        int base = pix * 65 + oct * 8;
        float gm = -1e30f;
        #pragma unroll
        for (int k = 0; k < 8; ++k) gm = fmaxf(gm, M[base + k]);
        float S = 0.f, T = 0.f, bi = 0.f, bm = -1e30f;
        #pragma unroll
        for (int k = 0; k < 8; ++k) {
            float mk = M[base + k];
            float wg = __expf(mk - gm);
            S += Sa[base + k] * wg;
            T += Ta[base + k] * wg;
            if (mk > bm) { bm = mk; bi = Ia[base + k]; }
        }
        P2m[pix * 9 + oct] = gm;
        P2s[pix * 9 + oct] = S;
        P2t[pix * 9 + oct] = T;
        P2i[pix * 9 + oct] = bi;
    }
    __syncthreads();

    // ---- stage 3: merge 8 octants, write out ----
    if (t < 8) {
        float gm = -1e30f;
        #pragma unroll
        for (int k = 0; k < 8; ++k) gm = fmaxf(gm, P2m[t * 9 + k]);
        float S = 0.f, T = 0.f, bi = 0.f, bm = -1e30f;
        #pragma unroll
        for (int k = 0; k < 8; ++k) {
            float mk = P2m[t * 9 + k];
            float wg = __expf(mk - gm);
            S += P2s[t * 9 + k] * wg;
            T += P2t[t * 9 + k] * wg;
            if (mk > bm) { bm = mk; bi = P2i[t * 9 + k]; }
        }
        out[pixbase + t] = T / S;           // pred_grid
        out[HW + pixbase + t] = bi;         // debug_assign
    }
}

extern "C" void kernel_launch(void* const* d_in, const int* in_sizes, int n_in,
                              void* d_out, int out_size, void* d_ws, size_t ws_size,
                              hipStream_t stream) {
    const float* qry   = (const float*)d_in[0];   // (1,1,256,128,128)
    const float* sup_x = (const float*)d_in[1];   // (1,5,1,256,128,128)
    float* out = (float*)d_out;                   // 16384 pred + 16384 assign

    float* praw = (float*)d_ws;                          // 320*256 fp32
    float* PT   = praw + NPROT * NCH;                    // 320*256 fp32 (transposed)
    float* sp   = PT + NPROT * NCH;                      // 320 fp32

    k_pool<<<5 * 256, 256, 0, stream>>>(sup_x, praw);
    k_norm<<<NPROT, 256, 0, stream>>>(praw, PT, sp);
    k_main<<<HW / 8, 256, 0, stream>>>(qry, PT, sp, out);
}

// Round 7
// 193.267 us; speedup vs baseline: 1.1792x; 1.1792x over previous
//
#include <hip/hip_runtime.h>

#define NCH   256
#define NPROT 320
#define HW    16384      // 128*128
#define TAU   20.0f
#define EPSN  1e-4f

// ---------------------------------------------------------------------------
// Kernel 1a: avg-pool sup_x (5,256,128,128) over 16x16 cells -> praw[p][c]
// One block per (s,c) plane. Fully coalesced float4 reads; no atomics.
// ---------------------------------------------------------------------------
__global__ __launch_bounds__(256) void k_pool(const float* __restrict__ sup_x,
                                              float* __restrict__ praw) {
    int b = blockIdx.x;            // s*256 + c
    int t = threadIdx.x;
    const float4* plane = (const float4*)(sup_x + (size_t)b * HW);
    float rsum[8];
    #pragma unroll
    for (int r = 0; r < 8; ++r) rsum[r] = 0.f;
    #pragma unroll
    for (int i = 0; i < 16; ++i) {
        float4 v = plane[i * 256 + t];          // h = i*8 + (t>>5), w4 = t&31
        rsum[i >> 1] += v.x + v.y + v.z + v.w;  // cell row R = h>>4 = i>>1
    }
    __shared__ float part[8][256];
    #pragma unroll
    for (int r = 0; r < 8; ++r) part[r][t] = rsum[r];
    __syncthreads();
    int R  = t >> 5;
    int cw = t & 31;               // = C*4 + bsub
    float s = 0.f;
    #pragma unroll
    for (int a = 0; a < 8; ++a) s += part[R][a * 32 + cw];
    s += __shfl_xor(s, 1);
    s += __shfl_xor(s, 2);
    if ((t & 3) == 0) {
        int shot = b >> 8, c = b & 255;
        int p = shot * 64 + R * 8 + (cw >> 2);
        praw[(size_t)p * NCH + c] = s * (1.0f / 256.0f);
    }
}

// ---------------------------------------------------------------------------
// Kernel 1b: per-proto center + safe-normalize; PT transposed (float4 per
// 4-channel block, proto-major within block); sp[p] = sum_c pro_n[p][c].
// ---------------------------------------------------------------------------
__device__ __forceinline__ float block_sum256(float x, float* ws4, int t) {
    #pragma unroll
    for (int o = 1; o < 64; o <<= 1) x += __shfl_xor(x, o);
    if ((t & 63) == 0) ws4[t >> 6] = x;
    __syncthreads();
    float r = ws4[0] + ws4[1] + ws4[2] + ws4[3];
    __syncthreads();
    return r;
}

__global__ __launch_bounds__(256) void k_norm(const float* __restrict__ praw,
                                              float* __restrict__ PT,
                                              float* __restrict__ sp) {
    int p = blockIdx.x;
    int c = threadIdx.x;
    __shared__ float ws4[4];
    float v = praw[p * NCH + c];
    float mean = block_sum256(v, ws4, c) * (1.0f / 256.0f);
    float cen = v - mean;
    float n2 = block_sum256(cen * cen, ws4, c);
    float inv = 1.0f / fmaxf(sqrtf(n2), EPSN);
    float pn = cen * inv;
    PT[(size_t)(c >> 2) * NPROT * 4 + p * 4 + (c & 3)] = pn;
    float ssum = block_sum256(pn, ws4, c);
    if (c == 0) sp[p] = ssum;
}

// ---------------------------------------------------------------------------
// Kernel 2: fused normalize(qry) -> 320 dots -> softmax-weighted mean + argmax
// 32 pixels/block, 256 threads = 4 waves (grid 512, 2 waves/SIMD).
// Wave w owns pixels w*8..w*8+7; lane l owns protos {l + 64j, j=0..4}.
// Software-pipelined K-loop: PT float4s for cb+1 are issued BEFORE the cb
// FMA burst (320 cyc), hiding the ~300-cyc L1/L2 latency inside the burst.
// Prefetch buffers are NAMED float4s (not arrays) to avoid the r3 scratch
// spill; accumulators are the spill-free r2 acc[8][5].
// ---------------------------------------------------------------------------
__global__ __launch_bounds__(256, 2) void k_main(const float* __restrict__ qry,
                                                 const float* __restrict__ PT,
                                                 const float* __restrict__ sp,
                                                 float* __restrict__ out) {
    // smem phases:
    //  phase A (staging + FMA): [0..8320) = qlds 32 x 260
    //                           [8320..8576) pm1, [8576..8832) ps1
    //  phase B (merge, after FMA): M/S/T/I: 4 arrays 32 x 65 at 0,2080,4160,6240
    //                              P2 m/s/t/i: 4 arrays 32 x 9 at 8320 + k*288
    __shared__ __align__(16) float smem[9472];
    __shared__ float meanv[32], invnv[32];
    int t = threadIdx.x;
    int pixbase = blockIdx.x * 32;

    // ---- stage 32 pixels x 256 channels (coalesced float4 over pixel dim) ----
    {
        int f4 = t & 7;            // which float4-of-pixels (0..7)
        int c0 = t >> 3;           // 0..31
        #pragma unroll
        for (int i = 0; i < 8; ++i) {
            int c = c0 + 32 * i;
            float4 v = *(const float4*)(qry + (size_t)c * HW + pixbase + f4 * 4);
            int px = f4 * 4;
            smem[(px + 0) * 260 + c] = v.x;
            smem[(px + 1) * 260 + c] = v.y;
            smem[(px + 2) * 260 + c] = v.z;
            smem[(px + 3) * 260 + c] = v.w;
        }
    }
    __syncthreads();

    // ---- per-pixel mean and inverse safe-norm ----
    {
        int pix = t & 31, sub = t >> 5;
        float s1 = 0.f, s2 = 0.f;
        #pragma unroll
        for (int j = 0; j < 32; ++j) {
            float q = smem[pix * 260 + sub * 32 + j];
            s1 += q; s2 += q * q;
        }
        smem[8320 + sub * 32 + pix] = s1;
        smem[8576 + sub * 32 + pix] = s2;
    }
    __syncthreads();
    if (t < 32) {
        float s1 = 0.f, s2 = 0.f;
        #pragma unroll
        for (int j = 0; j < 8; ++j) { s1 += smem[8320 + j * 32 + t]; s2 += smem[8576 + j * 32 + t]; }
        float mean = s1 * (1.0f / 256.0f);
        float n2 = fmaxf(s2 - s1 * mean, 0.f);   // sum (q-mean)^2
        meanv[t] = mean;
        invnv[t] = 1.0f / fmaxf(sqrtf(n2), EPSN);
    }
    __syncthreads();

    // ---- register-tiled, software-pipelined dots: 8 pixels x 5 protos ----
    int lane = t & 63;
    int w = t >> 6;
    float acc[8][5];
    #pragma unroll
    for (int i = 0; i < 8; ++i)
        #pragma unroll
        for (int j = 0; j < 5; ++j) acc[i][j] = 0.f;

    const float4* P4 = (const float4*)PT + lane;
    const float* qrow = smem + w * 8 * 260;

    // current PT fragments (named, not arrays)
    float4 p0 = P4[0], p1 = P4[64], p2 = P4[128], p3 = P4[192], p4 = P4[256];

#define BURST(CBX, V0, V1, V2, V3, V4)                                   \
    do {                                                                 \
        _Pragma("unroll")                                                \
        for (int i = 0; i < 8; ++i) {                                    \
            float4 qv = *(const float4*)(qrow + i * 260 + (CBX) * 4);    \
            acc[i][0] = fmaf(qv.x, V0.x, acc[i][0]);                     \
            acc[i][0] = fmaf(qv.y, V0.y, acc[i][0]);                     \
            acc[i][0] = fmaf(qv.z, V0.z, acc[i][0]);                     \
            acc[i][0] = fmaf(qv.w, V0.w, acc[i][0]);                     \
            acc[i][1] = fmaf(qv.x, V1.x, acc[i][1]);                     \
            acc[i][1] = fmaf(qv.y, V1.y, acc[i][1]);                     \
            acc[i][1] = fmaf(qv.z, V1.z, acc[i][1]);                     \
            acc[i][1] = fmaf(qv.w, V1.w, acc[i][1]);                     \
            acc[i][2] = fmaf(qv.x, V2.x, acc[i][2]);                     \
            acc[i][2] = fmaf(qv.y, V2.y, acc[i][2]);                     \
            acc[i][2] = fmaf(qv.z, V2.z, acc[i][2]);                     \
            acc[i][2] = fmaf(qv.w, V2.w, acc[i][2]);                     \
            acc[i][3] = fmaf(qv.x, V3.x, acc[i][3]);                     \
            acc[i][3] = fmaf(qv.y, V3.y, acc[i][3]);                     \
            acc[i][3] = fmaf(qv.z, V3.z, acc[i][3]);                     \
            acc[i][3] = fmaf(qv.w, V3.w, acc[i][3]);                     \
            acc[i][4] = fmaf(qv.x, V4.x, acc[i][4]);                     \
            acc[i][4] = fmaf(qv.y, V4.y, acc[i][4]);                     \
            acc[i][4] = fmaf(qv.z, V4.z, acc[i][4]);                     \
            acc[i][4] = fmaf(qv.w, V4.w, acc[i][4]);                     \
        }                                                                \
    } while (0)

    for (int cb = 0; cb < 64; cb += 2) {
        // issue PT loads for cb+1, then burn cb's FMA burst (latency hidden)
        const float4* Pn = P4 + (size_t)(cb + 1) * NPROT;
        float4 n0 = Pn[0], n1 = Pn[64], n2 = Pn[128], n3 = Pn[192], n4 = Pn[256];
        BURST(cb, p0, p1, p2, p3, p4);
        // issue PT loads for cb+2 (wrapped at the tail; the wrapped values
        // are never consumed), then burn cb+1's burst
        const float4* Pm = P4 + (size_t)((cb + 2) & 63) * NPROT;
        p0 = Pm[0]; p1 = Pm[64]; p2 = Pm[128]; p3 = Pm[192]; p4 = Pm[256];
        BURST(cb + 1, n0, n1, n2, n3, n4);
    }
#undef BURST

    // ---- per-thread softmax partials over 5 protos, per pixel ----
    float spv[5];
    #pragma unroll
    for (int j = 0; j < 5; ++j) spv[j] = sp[lane + 64 * j];

    float m8[8], S8[8], T8[8], I8[8];
    #pragma unroll
    for (int i = 0; i < 8; ++i) {
        int pix = w * 8 + i;
        float mean = meanv[pix], invn = invnv[pix];
        float d[5];
        float m = -1e30f; int bj = 0;
        #pragma unroll
        for (int j = 0; j < 5; ++j) {
            d[j] = TAU * invn * (acc[i][j] - mean * spv[j]);
            if (d[j] > m) { m = d[j]; bj = j; }
        }
        float S = 0.f, T = 0.f;
        #pragma unroll
        for (int j = 0; j < 5; ++j) {
            float e = __expf(d[j] - m);
            S += e; T += e * d[j];
        }
        m8[i] = m; S8[i] = S; T8[i] = T; I8[i] = (float)(lane + 64 * bj);
    }
    __syncthreads();   // everyone done reading qlds; safe to alias

    float* M  = smem;
    float* Sa = smem + 2080;
    float* Ta = smem + 4160;
    float* Ia = smem + 6240;
    #pragma unroll
    for (int i = 0; i < 8; ++i) {
        int pix = w * 8 + i;
        M [pix * 65 + lane] = m8[i];
        Sa[pix * 65 + lane] = S8[i];
        Ta[pix * 65 + lane] = T8[i];
        Ia[pix * 65 + lane] = I8[i];
    }
    __syncthreads();

    // ---- stage 2: merge 8 lanes per (pixel, octant) ----
    float* P2m = smem + 8320;
    float* P2s = smem + 8608;
    float* P2t = smem + 8896;
    float* P2i = smem + 9184;
    {
        int pix = t >> 3, oct = t & 7;
        int base = pix * 65 + oct * 8;
        float gm = -1e30f;
        #pragma unroll
        for (int k = 0; k < 8; ++k) gm = fmaxf(gm, M[base + k]);
        float S = 0.f, T = 0.f, bi = 0.f, bm = -1e30f;
        #pragma unroll
        for (int k = 0; k < 8; ++k) {
            float mk = M[base + k];
            float wg = __expf(mk - gm);
            S += Sa[base + k] * wg;
            T += Ta[base + k] * wg;
            if (mk > bm) { bm = mk; bi = Ia[base + k]; }
        }
        P2m[pix * 9 + oct] = gm;
        P2s[pix * 9 + oct] = S;
        P2t[pix * 9 + oct] = T;
        P2i[pix * 9 + oct] = bi;
    }
    __syncthreads();

    // ---- stage 3: merge 8 octants, write out ----
    if (t < 32) {
        float gm = -1e30f;
        #pragma unroll
        for (int k = 0; k < 8; ++k) gm = fmaxf(gm, P2m[t * 9 + k]);
        float S = 0.f, T = 0.f, bi = 0.f, bm = -1e30f;
        #pragma unroll
        for (int k = 0; k < 8; ++k) {
            float mk = P2m[t * 9 + k];
            float wg = __expf(mk - gm);
            S += P2s[t * 9 + k] * wg;
            T += P2t[t * 9 + k] * wg;
            if (mk > bm) { bm = mk; bi = P2i[t * 9 + k]; }
        }
        out[pixbase + t] = T / S;           // pred_grid
        out[HW + pixbase + t] = bi;         // debug_assign
    }
}

extern "C" void kernel_launch(void* const* d_in, const int* in_sizes, int n_in,
                              void* d_out, int out_size, void* d_ws, size_t ws_size,
                              hipStream_t stream) {
    const float* qry   = (const float*)d_in[0];   // (1,1,256,128,128)
    const float* sup_x = (const float*)d_in[1];   // (1,5,1,256,128,128)
    float* out = (float*)d_out;                   // 16384 pred + 16384 assign

    float* praw = (float*)d_ws;                          // 320*256 fp32
    float* PT   = praw + NPROT * NCH;                    // 320*256 fp32 (transposed)
    float* sp   = PT + NPROT * NCH;                      // 320 fp32

    k_pool<<<5 * 256, 256, 0, stream>>>(sup_x, praw);
    k_norm<<<NPROT, 256, 0, stream>>>(praw, PT, sp);
    k_main<<<HW / 32, 256, 0, stream>>>(qry, PT, sp, out);
}